// Round 10
// baseline (276.438 us; speedup 1.0000x reference)
//
#include <hip/hip_runtime.h>

// DropNorm: B=4096 rows, F=8192 features, fp32.
//   n = F/2; mu = sum(x*m)/n; sigma2 = sum(((x-mu)*m)^2)/(n-1)
//   out = gamma*m*(x-mu)*rsqrt(sigma2^2 + 1e-4) + beta   [sigma2 SQUARED: quirk]
//
// R13: GRID-STRIDE PERSISTENT STREAMS (the fill/m13 shape) — the one lever
// never tested. Ledger: structure x8, stores, occupancy 18->58%, traffic
// all ablated, all ~80us/2.5 TB/s. Everything that hits 6+ TB/s here is a
// grid-stride stream with no collective phase in a thread's lifetime.
//   pstats: 2048 blocks x 256 thr x 16 iters over the linear f4 array;
//     per wave-iter: 1KB chunk load (wave-uniform row), mask-nibble acc,
//     6-level butterfly, lane0 2x atomicAdd into acc[row]. No barriers/LDS.
//     (float-atomic order nondeterminism ~1e-5 rel << 0.0156 tolerance)
//   apply: copy+epsilon: x f4 + acc[row] (L2-hot) + nibble -> 6 FLOP +
//     rsqrt -> plain store. The in-harness known-good copy probe.
//   x read twice, but pass2 follows pass1 with only 32KB between -> best
//   possible L3 carry (134MB < 256MB).
// Pre-commit: apply >= ~55us or pstats >= ~40us -> streams cap at ~4 TB/s
// regardless of shape -> fused 80us is the practical ceiling -> declare
// ROOFLINE next round.

constexpr int Bn = 4096;
constexpr int Fn = 8192;
constexpr int NT = 256;             // threads per block
constexpr int GBLK = 2048;          // streaming grid (8 blocks/CU)
constexpr int GTHR = GBLK * NT;     // 524288 threads
constexpr int TOT4 = Bn * (Fn / 4); // 8388608 f4 total
constexpr int ITER = TOT4 / GTHR;   // 16 iterations, exact

typedef float f4 __attribute__((ext_vector_type(4)));

#define EPSV 1e-4f

__device__ inline int nzbytes(unsigned v) {
    return ((v & 0x000000ffu) != 0) + ((v & 0x0000ff00u) != 0) +
           ((v & 0x00ff0000u) != 0) + ((v & 0xff000000u) != 0);
}

// Prep: detect mask storage layout (uint8 bool vs int32), then:
//   mg[j]  = mask ? gamma[j] : 0.0          (Fn floats, fallback path)
//   acc[j] = 0                              (8192 floats: 2 per row, s/ss)
//   m4[p]  = 4 mask bits for f4 chunk p:    bit j = mask[4p+j]  (2048 B)
//   flags[0] = 1 iff gamma==1 && beta==0 everywhere (fast path)
// Detection: count nonzero among the first Fn BYTES. uint8 layout -> exactly
// Fn/2 = 4096; int32 layout -> those bytes span only 2048 ints -> count <= 2048.
__global__ __launch_bounds__(NT) void prep_kernel(const void* __restrict__ mask_raw,
                                                  const float* __restrict__ gamma,
                                                  const float* __restrict__ beta,
                                                  unsigned char* __restrict__ m4,
                                                  float* __restrict__ mg,
                                                  float* __restrict__ acc,
                                                  int* __restrict__ flags) {
    const unsigned char* mb = (const unsigned char*)mask_raw;
    const int* mi = (const int*)mask_raw;
    const uint4* mv = (const uint4*)mask_raw;
    const int tid = threadIdx.x;

    int cnt = 0;
#pragma unroll
    for (int k = 0; k < Fn / 16 / NT; ++k) {   // 2 iterations: first 8KB
        const uint4 w = mv[tid + k * NT];
        cnt += nzbytes(w.x) + nzbytes(w.y) + nzbytes(w.z) + nzbytes(w.w);
    }
    for (int off = 32; off > 0; off >>= 1) cnt += __shfl_down(cnt, off, 64);

    __shared__ int wc[NT / 64];
    __shared__ int flag;
    if ((tid & 63) == 0) wc[tid >> 6] = cnt;
    __syncthreads();
    if (tid == 0) {
        int total = wc[0] + wc[1] + wc[2] + wc[3];
        flag = (total == Fn / 2) ? 1 : 0;   // 1 = uint8 layout, 0 = int32 layout
    }
    __syncthreads();
    const bool u8 = (flag != 0);

    // mg materialize + acc zero (indices coincide: both Fn/gridDim slices...
    // acc is 2*Bn floats = 8192 = Fn, so same slice loop works)
    const int per_block = Fn / gridDim.x;
    const int base = blockIdx.x * per_block;
    for (int j = base + tid; j < base + per_block; j += NT) {
        const bool on = u8 ? (mb[j] != 0) : (mi[j] != 0);
        mg[j] = on ? gamma[j] : 0.0f;
        acc[j] = 0.0f;
    }

    // block 0: mask nibbles per f4 chunk (2048 bytes, 8 per thread)
    if (blockIdx.x == 0) {
#pragma unroll
        for (int t = 0; t < 8; ++t) {
            const int p = tid * 8 + t;
            unsigned b = 0;
#pragma unroll
            for (int j = 0; j < 4; ++j) {
                const int f = 4 * p + j;
                const bool on = u8 ? (mb[f] != 0) : (mi[f] != 0);
                b |= (on ? 1u : 0u) << j;
            }
            m4[p] = (unsigned char)b;
        }
    }

    // block 1: gamma/beta triviality scan (runtime-verified fast path)
    if (blockIdx.x == 1) {
        const f4* __restrict__ g4 = (const f4*)gamma;
        const f4* __restrict__ b4 = (const f4*)beta;
        int bad = 0;
#pragma unroll
        for (int k = 0; k < Fn / 4 / NT; ++k) {
            const f4 g = g4[tid + k * NT];
            const f4 b = b4[tid + k * NT];
            bad |= (g.x != 1.0f) | (g.y != 1.0f) | (g.z != 1.0f) | (g.w != 1.0f);
            bad |= (b.x != 0.0f) | (b.y != 0.0f) | (b.z != 0.0f) | (b.w != 0.0f);
        }
        __shared__ int anybad;
        if (tid == 0) anybad = 0;
        __syncthreads();
        if (bad) atomicOr(&anybad, 1);
        __syncthreads();
        if (tid == 0) flags[0] = anybad ? 0 : 1;
    }
}

// Pass 1: grid-stride masked partial stats. Per wave-iteration the 64 lanes
// cover one aligned 64-f4 chunk (wave-uniform row: 2048 f4/row, chunks never
// straddle rows). Butterfly -> lane0 atomicAdds {s,ss} into acc[row].
__global__ __launch_bounds__(NT) void pstats_kernel(const float* __restrict__ x,
                                                    const unsigned char* __restrict__ m4,
                                                    float* __restrict__ acc) {
    const int gid = blockIdx.x * NT + threadIdx.x;
    const int lane = threadIdx.x & 63;
#pragma unroll 4
    for (int i = 0; i < ITER; ++i) {
        const int idx = gid + i * GTHR;
        const f4 v = ((const f4*)x)[idx];
        const unsigned mb = m4[idx & (Fn / 4 - 1)];   // L1-hot 2KB table
        const float a0 = (mb & 1u) ? v.x : 0.f;
        const float a1 = (mb & 2u) ? v.y : 0.f;
        const float a2 = (mb & 4u) ? v.z : 0.f;
        const float a3 = (mb & 8u) ? v.w : 0.f;
        float s  = (a0 + a1) + (a2 + a3);
        float ss = (a0 * a0 + a1 * a1) + (a2 * a2 + a3 * a3);
        for (int off = 32; off > 0; off >>= 1) {
            s  += __shfl_xor(s, off, 64);
            ss += __shfl_xor(ss, off, 64);
        }
        if (lane == 0) {
            const int row = idx >> 11;                // 2048 f4 per row
            atomicAdd(&acc[2 * row], s);
            atomicAdd(&acc[2 * row + 1], ss);
        }
    }
}

// Pass 2: grid-stride copy+epsilon. acc[row] is final (kernel boundary).
// Wave-uniform row -> acc loads are broadcast, L2-hot.
__global__ __launch_bounds__(NT) void apply_kernel(const float* __restrict__ x,
                                                   const unsigned char* __restrict__ m4,
                                                   const float* __restrict__ mg,
                                                   const float* __restrict__ beta,
                                                   const float* __restrict__ acc,
                                                   const int* __restrict__ flags,
                                                   float* __restrict__ out) {
    const int gid = blockIdx.x * NT + threadIdx.x;
    const float nf = (float)(Fn / 2);
    const int triv = flags[0];

    if (triv) {
        // fast path (gamma==1, beta==0): out = maskbit ? (x-mu)*inv : 0
#pragma unroll 4
        for (int i = 0; i < ITER; ++i) {
            const int idx = gid + i * GTHR;
            const int row = idx >> 11;
            const f4 v = ((const f4*)x)[idx];
            const float s  = acc[2 * row];
            const float ss = acc[2 * row + 1];
            const unsigned mb = m4[idx & (Fn / 4 - 1)];
            const float mu = s * (1.0f / nf);
            const float sigma2 = (ss - nf * mu * mu) * (1.0f / (nf - 1.0f));
            const float inv = rsqrtf(sigma2 * sigma2 + EPSV);  // quirk: ^2
            f4 o;
            o.x = (mb & 1u) ? (v.x - mu) * inv : 0.f;
            o.y = (mb & 2u) ? (v.y - mu) * inv : 0.f;
            o.z = (mb & 4u) ? (v.z - mu) * inv : 0.f;
            o.w = (mb & 8u) ? (v.w - mu) * inv : 0.f;
            ((f4*)out)[idx] = o;                      // plain store (fill path)
        }
    } else {
        // general path: out = mg*(x-mu)*inv + beta  (mg = mask?gamma:0)
#pragma unroll 4
        for (int i = 0; i < ITER; ++i) {
            const int idx = gid + i * GTHR;
            const int row = idx >> 11;
            const int p = idx & (Fn / 4 - 1);
            const f4 v = ((const f4*)x)[idx];
            const f4 g = ((const f4*)mg)[p];
            const f4 b = ((const f4*)beta)[p];
            const float s  = acc[2 * row];
            const float ss = acc[2 * row + 1];
            const float mu = s * (1.0f / nf);
            const float sigma2 = (ss - nf * mu * mu) * (1.0f / (nf - 1.0f));
            const float inv = rsqrtf(sigma2 * sigma2 + EPSV);  // quirk: ^2
            f4 o;
            o.x = g.x * (v.x - mu) * inv + b.x;
            o.y = g.y * (v.y - mu) * inv + b.y;
            o.z = g.z * (v.z - mu) * inv + b.z;
            o.w = g.w * (v.w - mu) * inv + b.w;
            ((f4*)out)[idx] = o;
        }
    }
}

extern "C" void kernel_launch(void* const* d_in, const int* in_sizes, int n_in,
                              void* d_out, int out_size, void* d_ws, size_t ws_size,
                              hipStream_t stream) {
    const float* x     = (const float*)d_in[0];
    const float* gamma = (const float*)d_in[1];
    const float* beta  = (const float*)d_in[2];
    const void*  mask  = d_in[3];
    float* out = (float*)d_out;

    float* mg = (float*)d_ws;                          // Fn floats   (32 KB)
    float* acc = mg + Fn;                              // Fn floats   (32 KB; 2/row)
    unsigned char* m4 = (unsigned char*)(acc + Fn);    // 2048 B
    int* flags = (int*)(m4 + 2048);                    // 4 B

    prep_kernel<<<16, NT, 0, stream>>>(mask, gamma, beta, m4, mg, acc, flags);
    pstats_kernel<<<GBLK, NT, 0, stream>>>(x, m4, acc);
    apply_kernel<<<GBLK, NT, 0, stream>>>(x, m4, mg, beta, acc, flags, out);
}